// Round 3
// baseline (29.225 us; speedup 1.0000x reference)
//
#include <hip/hip_runtime.h>

#define BSZ  8
#define LSEQ 2048
#define DM   256
#define NS   16
#define NC   32          // chunks along L
#define LC   (LSEQ/NC)   // 64 timesteps per chunk

// ---------------------------------------------------------------------------
// Pass 1: per-(b,d,chunk) local scan with h=0 init; emit carry h_out[16].
// carry layout: [b][chunk][n][d]  (d contiguous -> coalesced)
// ---------------------------------------------------------------------------
__global__ __launch_bounds__(DM) void k_local(
        const float* __restrict__ x,
        const float* __restrict__ A,
        const float* __restrict__ Bm,
        const float* __restrict__ delta,
        float* __restrict__ carry) {
    const int d     = threadIdx.x;
    const int chunk = blockIdx.x & (NC - 1);
    const int b     = blockIdx.x / NC;

    const float dt = 1.0f / (1.0f + expf(-delta[d]));
    float a[NS], bb[NS];
#pragma unroll
    for (int n = 0; n < NS; ++n) {
        a[n]  = expf(dt * A[d * NS + n]);
        bb[n] = dt * Bm[d * NS + n];
    }

    float h[NS];
#pragma unroll
    for (int n = 0; n < NS; ++n) h[n] = 0.0f;

    const float* xp = x + ((size_t)(b * LSEQ + chunk * LC)) * DM + d;
#pragma unroll 4
    for (int t = 0; t < LC; ++t) {
        const float xv = xp[(size_t)t * DM];
#pragma unroll
        for (int n = 0; n < NS; ++n) h[n] = fmaf(a[n], h[n], bb[n] * xv);
    }

    float* cp = carry + ((size_t)(b * NC + chunk) * NS) * DM + d;
#pragma unroll
    for (int n = 0; n < NS; ++n) cp[(size_t)n * DM] = h[n];
}

// ---------------------------------------------------------------------------
// Pass 2: per-(b,n,d) sequential prefix over the NC chunk carries, in place.
// After this, carry[b][j][n][d] holds the state at the START of chunk j.
// a^LC computed directly as exp(dt*A*LC).
// ---------------------------------------------------------------------------
__global__ __launch_bounds__(256) void k_prefix(
        const float* __restrict__ A,
        const float* __restrict__ delta,
        float* __restrict__ carry) {
    const int tid = blockIdx.x * 256 + threadIdx.x;   // 0 .. BSZ*NS*DM-1
    const int d = tid & (DM - 1);
    const int n = (tid >> 8) & (NS - 1);
    const int b = tid >> 12;

    const float dt = 1.0f / (1.0f + expf(-delta[d]));
    const float aL = expf(dt * A[d * NS + n] * (float)LC);

    float run = 0.0f;
    float* cp = carry + (size_t)b * NC * NS * DM + (size_t)n * DM + d;
    for (int j = 0; j < NC; ++j) {
        const size_t off = (size_t)j * NS * DM;
        const float c = cp[off];
        cp[off] = run;                 // state entering chunk j
        run = fmaf(aL, run, c);        // state leaving chunk j
    }
}

// ---------------------------------------------------------------------------
// Pass 3: re-run the local scan seeded with the chunk-entry state; write y.
// y_t = <h_t, C_d> + D_d * x_t
// ---------------------------------------------------------------------------
__global__ __launch_bounds__(DM) void k_final(
        const float* __restrict__ x,
        const float* __restrict__ A,
        const float* __restrict__ Bm,
        const float* __restrict__ Cm,
        const float* __restrict__ Dv,
        const float* __restrict__ delta,
        const float* __restrict__ hin,
        float* __restrict__ y) {
    const int d     = threadIdx.x;
    const int chunk = blockIdx.x & (NC - 1);
    const int b     = blockIdx.x / NC;

    const float dt = 1.0f / (1.0f + expf(-delta[d]));
    float a[NS], bb[NS], cc[NS];
#pragma unroll
    for (int n = 0; n < NS; ++n) {
        a[n]  = expf(dt * A[d * NS + n]);
        bb[n] = dt * Bm[d * NS + n];
        cc[n] = Cm[d * NS + n];
    }
    const float Dd = Dv[d];

    float h[NS];
    const float* hp = hin + ((size_t)(b * NC + chunk) * NS) * DM + d;
#pragma unroll
    for (int n = 0; n < NS; ++n) h[n] = hp[(size_t)n * DM];

    const size_t base = ((size_t)(b * LSEQ + chunk * LC)) * DM + d;
    const float* xp = x + base;
    float*       yp = y + base;
#pragma unroll 4
    for (int t = 0; t < LC; ++t) {
        const float xv = xp[(size_t)t * DM];
        float acc = Dd * xv;
#pragma unroll
        for (int n = 0; n < NS; ++n) {
            h[n] = fmaf(a[n], h[n], bb[n] * xv);
            acc  = fmaf(h[n], cc[n], acc);
        }
        yp[(size_t)t * DM] = acc;
    }
}

// ---------------------------------------------------------------------------
extern "C" void kernel_launch(void* const* d_in, const int* in_sizes, int n_in,
                              void* d_out, int out_size, void* d_ws, size_t ws_size,
                              hipStream_t stream) {
    const float* x     = (const float*)d_in[0];
    const float* A     = (const float*)d_in[1];
    const float* Bm    = (const float*)d_in[2];
    const float* Cm    = (const float*)d_in[3];
    const float* Dv    = (const float*)d_in[4];
    const float* delta = (const float*)d_in[5];
    float* y = (float*)d_out;

    float* carry = (float*)d_ws;   // needs BSZ*NC*NS*DM*4 = 4 MiB

    dim3 blk(DM);
    dim3 grd1(BSZ * NC);                 // 256 blocks
    k_local<<<grd1, blk, 0, stream>>>(x, A, Bm, delta, carry);

    dim3 grd2((BSZ * NS * DM) / 256);    // 128 blocks
    k_prefix<<<grd2, dim3(256), 0, stream>>>(A, delta, carry);

    k_final<<<grd1, blk, 0, stream>>>(x, A, Bm, Cm, Dv, delta, carry, y);
}